// Round 1
// baseline (5083.109 us; speedup 1.0000x reference)
//
#include <hip/hip_runtime.h>
#include <hip/hip_bf16.h>
#include <math.h>

#define DIMM   1024
#define NHEADS 16
#define DHEAD  64
#define BATCH  2
#define SEQ    2048
#define NKEYS  (SEQ + 1)      // 2049 (null + seq)
#define PBROWS (2 * SEQ - 1)  // 4095
#define ROWS   (BATCH * SEQ)  // 4096

// ---------------------------------------------------------------------------
// LayerNorm over last dim (=1024), one block per row, 256 threads, float4.
// Optional pre-bias add (addb may be null) and optional silu epilogue.
// ---------------------------------------------------------------------------
__global__ __launch_bounds__(256) void ln_kernel(
    const float* __restrict__ in, const float* __restrict__ addb,
    const float* __restrict__ g, const float* __restrict__ bvec,
    float* __restrict__ out, int silu) {
  int row = blockIdx.x;
  int t = threadIdx.x;
  float4 x = ((const float4*)(in + (size_t)row * DIMM))[t];
  if (addb) {
    float4 a = ((const float4*)addb)[t];
    x.x += a.x; x.y += a.y; x.z += a.z; x.w += a.w;
  }
  float s  = x.x + x.y + x.z + x.w;
  float ss = x.x * x.x + x.y * x.y + x.z * x.z + x.w * x.w;
#pragma unroll
  for (int off = 32; off > 0; off >>= 1) {
    s  += __shfl_down(s, off);
    ss += __shfl_down(ss, off);
  }
  __shared__ float rs[4], rss[4];
  int wv = t >> 6, lane = t & 63;
  if (lane == 0) { rs[wv] = s; rss[wv] = ss; }
  __syncthreads();
  float S  = rs[0] + rs[1] + rs[2] + rs[3];
  float SS = rss[0] + rss[1] + rss[2] + rss[3];
  float mu  = S * (1.0f / DIMM);
  float var = SS * (1.0f / DIMM) - mu * mu;
  float inv = rsqrtf(var + 1e-5f);
  float4 gv = ((const float4*)g)[t];
  float4 bv = ((const float4*)bvec)[t];
  float4 o;
  o.x = (x.x - mu) * inv * gv.x + bv.x;
  o.y = (x.y - mu) * inv * gv.y + bv.y;
  o.z = (x.z - mu) * inv * gv.z + bv.z;
  o.w = (x.w - mu) * inv * gv.w + bv.w;
  if (silu) {
    o.x = o.x / (1.f + expf(-o.x));
    o.y = o.y / (1.f + expf(-o.y));
    o.z = o.z / (1.f + expf(-o.z));
    o.w = o.w / (1.f + expf(-o.w));
  }
  ((float4*)(out + (size_t)row * DIMM))[t] = o;
}

// ---------------------------------------------------------------------------
// Tiled f32 GEMM: C[M][N] = A[M][K] @ B[K][N].  64x64 tile, BK=16,
// 256 threads, 4x4 per thread.  M may be non-multiple of 64 (guarded).
// ---------------------------------------------------------------------------
__global__ __launch_bounds__(256) void gemm_f32(
    const float* __restrict__ A, const float* __restrict__ B,
    float* __restrict__ C, int M, int N, int K) {
  __shared__ float As[16][64];
  __shared__ float Bs[16][64];
  int tx = threadIdx.x & 15, ty = threadIdx.x >> 4;
  int row0 = blockIdx.y * 64, col0 = blockIdx.x * 64;
  float acc[4][4] = {};
  for (int k0 = 0; k0 < K; k0 += 16) {
    for (int l = threadIdx.x; l < 64 * 16; l += 256) {
      int r = l >> 4, kk = l & 15;
      As[kk][r] = (row0 + r < M) ? A[(size_t)(row0 + r) * K + k0 + kk] : 0.f;
    }
    for (int l = threadIdx.x; l < 16 * 64; l += 256) {
      int kk = l >> 6, c = l & 63;
      Bs[kk][c] = B[(size_t)(k0 + kk) * N + col0 + c];
    }
    __syncthreads();
#pragma unroll
    for (int kk = 0; kk < 16; ++kk) {
      float a[4], bb[4];
#pragma unroll
      for (int i = 0; i < 4; i++) a[i] = As[kk][ty * 4 + i];
#pragma unroll
      for (int j = 0; j < 4; j++) bb[j] = Bs[kk][tx * 4 + j];
#pragma unroll
      for (int i = 0; i < 4; i++)
#pragma unroll
        for (int j = 0; j < 4; j++) acc[i][j] += a[i] * bb[j];
    }
    __syncthreads();
  }
  for (int i = 0; i < 4; i++) {
    int r = row0 + ty * 4 + i;
    if (r < M)
      for (int j = 0; j < 4; j++)
        C[(size_t)r * N + col0 + tx * 4 + j] = acc[i][j];
  }
}

// ---------------------------------------------------------------------------
// q relayout: tmp[b*SEQ+i][h*64+d] -> qb[((b*16+h)*SEQ+i)*64+d], * scale
// ---------------------------------------------------------------------------
__global__ __launch_bounds__(256) void relayout_q(
    const float* __restrict__ tmp, float* __restrict__ qb) {
  size_t e = (size_t)blockIdx.x * 256 + threadIdx.x;  // float4 index
  int m = (int)(e >> 8), c4 = (int)(e & 255);
  int b = m >> 11, i = m & 2047;
  int h = c4 >> 4, d4 = c4 & 15;
  float4 v = ((const float4*)tmp)[e];
  const float sc = 0.125f;  // 64^-0.5
  v.x *= sc; v.y *= sc; v.z *= sc; v.w *= sc;
  ((float4*)qb)[(((size_t)(b * NHEADS + h) * SEQ + i) << 4) + d4] = v;
}

// kv relayout: tmpkv[b*SEQ+i][c] -> k[b][i+1][c] (c<64) / v[b][i+1][c-64]
__global__ __launch_bounds__(256) void relayout_kv(
    const float* __restrict__ tmpkv, float* __restrict__ kb,
    float* __restrict__ vb) {
  size_t e = (size_t)blockIdx.x * 256 + threadIdx.x;  // float4 index
  int m = (int)(e >> 5), c4 = (int)(e & 31);
  int b = m >> 11, i = m & 2047;
  float4 v = ((const float4*)tmpkv)[e];
  size_t rowbase = ((size_t)b * NKEYS + (i + 1)) << 4;
  if (c4 < 16) ((float4*)kb)[rowbase + c4] = v;
  else         ((float4*)vb)[rowbase + (c4 - 16)] = v;
}

__global__ void fill_null(const float* __restrict__ null_kv,
                          float* __restrict__ kb, float* __restrict__ vb) {
  int b = blockIdx.x, d = threadIdx.x;  // 2 blocks x 64
  kb[(size_t)b * NKEYS * DHEAD + d] = null_kv[d];
  vb[(size_t)b * NKEYS * DHEAD + d] = null_kv[DHEAD + d];
}

// pos-bias pre: out[r][c] = (r - (SEQ-1)) * w0[c] + b0[c]
__global__ __launch_bounds__(256) void posbias_pre(
    const float* __restrict__ w0, const float* __restrict__ b0,
    float* __restrict__ out) {
  int r = blockIdx.x, t = threadIdx.x;
  float p = (float)(r - (SEQ - 1));
  float4 w = ((const float4*)w0)[t];
  float4 bb = ((const float4*)b0)[t];
  float4 o;
  o.x = p * w.x + bb.x; o.y = p * w.y + bb.y;
  o.z = p * w.z + bb.z; o.w = p * w.w + bb.w;
  ((float4*)(out + (size_t)r * DIMM))[t] = o;
}

// h2: bias_tab[r][col] = h1[r][:] . w2[:][col] + b2[col]   (cols = 16)
__global__ __launch_bounds__(256) void h2_kernel(
    const float* __restrict__ h1, const float* __restrict__ w2,
    const float* __restrict__ b2, float* __restrict__ bias_tab) {
  int r = blockIdx.x, t = threadIdx.x;
  int col = t & 15, seg = t >> 4;  // 16 segs of 64
  const float* hr = h1 + (size_t)r * DIMM;
  float acc = 0.f;
  for (int k = seg * 64; k < seg * 64 + 64; ++k)
    acc += hr[k] * w2[(size_t)k * NHEADS + col];
  __shared__ float p[16][16];
  p[seg][col] = acc;
  __syncthreads();
  if (t < 16) {
    float s = 0.f;
#pragma unroll
    for (int q = 0; q < 16; q++) s += p[q][t];
    bias_tab[(size_t)r * NHEADS + t] = s + b2[t];
  }
}

// ---------------------------------------------------------------------------
// Attention: one block per (b, h, i).  Only unmasked prefix j in [0, i+1].
// ---------------------------------------------------------------------------
__global__ __launch_bounds__(256) void attn_kernel(
    const float* __restrict__ qb, const float* __restrict__ kb,
    const float* __restrict__ vb, const float* __restrict__ bias_tab,
    const float* __restrict__ null_bias, float* __restrict__ outb) {
  const int i = blockIdx.x, h = blockIdx.y, b = blockIdx.z;
  __shared__ float qs[DHEAD];
  __shared__ float sc[NKEYS];
  __shared__ float rmax[4], rsum[4];
  __shared__ float pacc[4][DHEAD];
  int t = threadIdx.x;
  if (t < DHEAD)
    qs[t] = qb[((size_t)(b * NHEADS + h) * SEQ + i) * DHEAD + t];
  __syncthreads();
  const int nv = i + 2;  // valid keys: j = 0 .. i+1
  const float* Kp = kb + (size_t)b * NKEYS * DHEAD;
  float lmax = -3.0e38f;
  float nb = null_bias[h];
  for (int j = t; j < nv; j += 256) {
    const float4* kr = (const float4*)(Kp + (size_t)j * DHEAD);
    float s = 0.f;
#pragma unroll
    for (int u = 0; u < 16; ++u) {
      float4 k4 = kr[u];
      float4 q4 = ((const float4*)qs)[u];
      s += q4.x * k4.x + q4.y * k4.y + q4.z * k4.z + q4.w * k4.w;
    }
    s += (j == 0) ? nb : bias_tab[(size_t)(i - j + SEQ) * NHEADS + h];
    sc[j] = s;
    lmax = fmaxf(lmax, s);
  }
#pragma unroll
  for (int off = 32; off > 0; off >>= 1)
    lmax = fmaxf(lmax, __shfl_down(lmax, off));
  int wv = t >> 6, lane = t & 63;
  if (lane == 0) rmax[wv] = lmax;
  __syncthreads();
  float M = fmaxf(fmaxf(rmax[0], rmax[1]), fmaxf(rmax[2], rmax[3]));
  float lsum = 0.f;
  for (int j = t; j < nv; j += 256) {
    float pp = expf(sc[j] - M);
    sc[j] = pp;
    lsum += pp;
  }
#pragma unroll
  for (int off = 32; off > 0; off >>= 1) lsum += __shfl_down(lsum, off);
  if (lane == 0) rsum[wv] = lsum;
  __syncthreads();  // also makes all sc[] writes visible
  float denom = rsum[0] + rsum[1] + rsum[2] + rsum[3];
  int d = t & 63, ch = t >> 6;
  const float* Vp = vb + (size_t)b * NKEYS * DHEAD;
  float acc = 0.f;
  for (int j = ch; j < nv; j += 4) acc += sc[j] * Vp[(size_t)j * DHEAD + d];
  pacc[ch][d] = acc;
  __syncthreads();
  if (t < DHEAD) {
    float o = (pacc[0][t] + pacc[1][t] + pacc[2][t] + pacc[3][t]) / denom;
    outb[((size_t)(b * SEQ + i)) * DIMM + h * DHEAD + t] = o;
  }
}

// ---------------------------------------------------------------------------
extern "C" void kernel_launch(void* const* d_in, const int* in_sizes, int n_in,
                              void* d_out, int out_size, void* d_ws,
                              size_t ws_size, hipStream_t stream) {
  const float* x         = (const float*)d_in[0];
  const float* ln_g      = (const float*)d_in[1];
  const float* ln_b      = (const float*)d_in[2];
  const float* Wq        = (const float*)d_in[3];
  const float* Wkv       = (const float*)d_in[4];
  const float* null_kv   = (const float*)d_in[5];
  const float* null_bias = (const float*)d_in[6];
  const float* pb_w0     = (const float*)d_in[7];
  const float* pb_b0     = (const float*)d_in[8];
  const float* pb_ln0_g  = (const float*)d_in[9];
  const float* pb_ln0_b  = (const float*)d_in[10];
  const float* pb_w1     = (const float*)d_in[11];
  const float* pb_b1     = (const float*)d_in[12];
  const float* pb_ln1_g  = (const float*)d_in[13];
  const float* pb_ln1_b  = (const float*)d_in[14];
  const float* pb_w2     = (const float*)d_in[15];
  const float* pb_b2     = (const float*)d_in[16];
  const float* Wo        = (const float*)d_in[17];
  const float* out_ln_g  = (const float*)d_in[18];
  const float* out_ln_b  = (const float*)d_in[19];
  float* out = (float*)d_out;

  float* ws = (float*)d_ws;
  float* xn       = ws;                 // 4096*1024
  float* tmpA     = ws + 4194304;       // 4096*1024 (q-pre / h1-pre / attn-out)
  float* qb       = ws + 8388608;       // 4096*1024 (q / final-pre)
  float* h0       = ws + 12582912;      // 4095*1024
  float* tmpKV    = ws + 16776192;      // 4096*128
  float* kb       = ws + 17300480;      // 2*2049*64
  float* vb       = ws + 17562752;      // 2*2049*64
  float* bias_tab = ws + 17825024;      // 4095*16

  // 1. xn = LN(x)
  ln_kernel<<<ROWS, 256, 0, stream>>>(x, nullptr, ln_g, ln_b, xn, 0);
  // 2. q = xn @ Wq  (scale folded into relayout)
  gemm_f32<<<dim3(DIMM / 64, ROWS / 64), 256, 0, stream>>>(xn, Wq, tmpA, ROWS,
                                                           DIMM, DIMM);
  relayout_q<<<4096, 256, 0, stream>>>(tmpA, qb);
  // 3. kv = xn @ Wkv ; split + null prepend
  gemm_f32<<<dim3(2, ROWS / 64), 256, 0, stream>>>(xn, Wkv, tmpKV, ROWS, 128,
                                                   DIMM);
  relayout_kv<<<512, 256, 0, stream>>>(tmpKV, kb, vb);
  fill_null<<<2, 64, 0, stream>>>(null_kv, kb, vb);
  // 4. dynamic pos-bias MLP -> bias_tab
  posbias_pre<<<PBROWS, 256, 0, stream>>>(pb_w0, pb_b0, h0);
  ln_kernel<<<PBROWS, 256, 0, stream>>>(h0, nullptr, pb_ln0_g, pb_ln0_b, h0, 1);
  gemm_f32<<<dim3(DIMM / 64, (PBROWS + 63) / 64), 256, 0, stream>>>(
      h0, pb_w1, tmpA, PBROWS, DIMM, DIMM);
  ln_kernel<<<PBROWS, 256, 0, stream>>>(tmpA, pb_b1, pb_ln1_g, pb_ln1_b, h0, 1);
  h2_kernel<<<PBROWS, 256, 0, stream>>>(h0, pb_w2, pb_b2, bias_tab);
  // 5. attention -> tmpA  (b, n, INNER layout)
  attn_kernel<<<dim3(SEQ, NHEADS, BATCH), 256, 0, stream>>>(
      qb, kb, vb, bias_tab, null_bias, tmpA);
  // 6. out = LN(attn_out @ Wo)
  gemm_f32<<<dim3(DIMM / 64, ROWS / 64), 256, 0, stream>>>(tmpA, Wo, qb, ROWS,
                                                           DIMM, DIMM);
  ln_kernel<<<ROWS, 256, 0, stream>>>(qb, nullptr, out_ln_g, out_ln_b, out, 0);
}

// Round 2
// 1345.608 us; speedup vs baseline: 3.7776x; 3.7776x over previous
//
#include <hip/hip_runtime.h>
#include <hip/hip_bf16.h>
#include <math.h>

#define DIMM   1024
#define NHEADS 16
#define DHEAD  64
#define BATCH  2
#define SEQ    2048
#define NKEYS  (SEQ + 1)      // 2049 (null + seq)
#define NKROWS 2112           // padded K rows (last tile reads to 2111)
#define NKP    2112           // padded key count for V^T inner dim
#define PBROWS (2 * SEQ - 1)  // 4095
#define ROWS   (BATCH * SEQ)  // 4096

using bf16x8 = __attribute__((ext_vector_type(8))) short;
using f32x4  = __attribute__((ext_vector_type(4))) float;

__device__ __forceinline__ unsigned short f2bf(float f) {
  __hip_bfloat16 h = __float2bfloat16(f);
  return __builtin_bit_cast(unsigned short, h);
}

// ---------------------------------------------------------------------------
// LayerNorm over last dim (=1024), one block per row, 256 threads, float4.
// ---------------------------------------------------------------------------
__global__ __launch_bounds__(256) void ln_kernel(
    const float* __restrict__ in, const float* __restrict__ addb,
    const float* __restrict__ g, const float* __restrict__ bvec,
    float* __restrict__ out, int silu) {
  int row = blockIdx.x;
  int t = threadIdx.x;
  float4 x = ((const float4*)(in + (size_t)row * DIMM))[t];
  if (addb) {
    float4 a = ((const float4*)addb)[t];
    x.x += a.x; x.y += a.y; x.z += a.z; x.w += a.w;
  }
  float s  = x.x + x.y + x.z + x.w;
  float ss = x.x * x.x + x.y * x.y + x.z * x.z + x.w * x.w;
#pragma unroll
  for (int off = 32; off > 0; off >>= 1) {
    s  += __shfl_down(s, off);
    ss += __shfl_down(ss, off);
  }
  __shared__ float rs[4], rss[4];
  int wv = t >> 6, lane = t & 63;
  if (lane == 0) { rs[wv] = s; rss[wv] = ss; }
  __syncthreads();
  float S  = rs[0] + rs[1] + rs[2] + rs[3];
  float SS = rss[0] + rss[1] + rss[2] + rss[3];
  float mu  = S * (1.0f / DIMM);
  float var = SS * (1.0f / DIMM) - mu * mu;
  float inv = rsqrtf(var + 1e-5f);
  float4 gv = ((const float4*)g)[t];
  float4 bv = ((const float4*)bvec)[t];
  float4 o;
  o.x = (x.x - mu) * inv * gv.x + bv.x;
  o.y = (x.y - mu) * inv * gv.y + bv.y;
  o.z = (x.z - mu) * inv * gv.z + bv.z;
  o.w = (x.w - mu) * inv * gv.w + bv.w;
  if (silu) {
    o.x = o.x / (1.f + expf(-o.x));
    o.y = o.y / (1.f + expf(-o.y));
    o.z = o.z / (1.f + expf(-o.z));
    o.w = o.w / (1.f + expf(-o.w));
  }
  ((float4*)(out + (size_t)row * DIMM))[t] = o;
}

// ---------------------------------------------------------------------------
// Tiled f32 GEMM: C[M][N] = A[M][K] @ B[K][N].  64x64 tile, BK=16.
// ---------------------------------------------------------------------------
__global__ __launch_bounds__(256) void gemm_f32(
    const float* __restrict__ A, const float* __restrict__ B,
    float* __restrict__ C, int M, int N, int K) {
  __shared__ float As[16][64];
  __shared__ float Bs[16][64];
  int tx = threadIdx.x & 15, ty = threadIdx.x >> 4;
  int row0 = blockIdx.y * 64, col0 = blockIdx.x * 64;
  float acc[4][4] = {};
  for (int k0 = 0; k0 < K; k0 += 16) {
    for (int l = threadIdx.x; l < 64 * 16; l += 256) {
      int r = l >> 4, kk = l & 15;
      As[kk][r] = (row0 + r < M) ? A[(size_t)(row0 + r) * K + k0 + kk] : 0.f;
    }
    for (int l = threadIdx.x; l < 16 * 64; l += 256) {
      int kk = l >> 6, c = l & 63;
      Bs[kk][c] = B[(size_t)(k0 + kk) * N + col0 + c];
    }
    __syncthreads();
#pragma unroll
    for (int kk = 0; kk < 16; ++kk) {
      float a[4], bb[4];
#pragma unroll
      for (int i = 0; i < 4; i++) a[i] = As[kk][ty * 4 + i];
#pragma unroll
      for (int j = 0; j < 4; j++) bb[j] = Bs[kk][tx * 4 + j];
#pragma unroll
      for (int i = 0; i < 4; i++)
#pragma unroll
        for (int j = 0; j < 4; j++) acc[i][j] += a[i] * bb[j];
    }
    __syncthreads();
  }
  for (int i = 0; i < 4; i++) {
    int r = row0 + ty * 4 + i;
    if (r < M)
      for (int j = 0; j < 4; j++)
        C[(size_t)r * N + col0 + tx * 4 + j] = acc[i][j];
  }
}

// ---------------------------------------------------------------------------
// q relayout -> bf16 [b][h][i][d], scaled by 1/8
// ---------------------------------------------------------------------------
__global__ __launch_bounds__(256) void relayout_q(
    const float* __restrict__ tmp, unsigned short* __restrict__ qb) {
  size_t e = (size_t)blockIdx.x * 256 + threadIdx.x;  // float4 index
  int m = (int)(e >> 8), c4 = (int)(e & 255);
  int b = m >> 11, i = m & 2047;
  int h = c4 >> 4, d4 = c4 & 15;
  float4 v = ((const float4*)tmp)[e];
  const float sc = 0.125f;  // 64^-0.5
  ushort4 o;
  o.x = f2bf(v.x * sc); o.y = f2bf(v.y * sc);
  o.z = f2bf(v.z * sc); o.w = f2bf(v.w * sc);
  ((ushort4*)qb)[((size_t)(b * NHEADS + h) * SEQ + i) * 16 + d4] = o;
}

// kv relayout: k -> bf16 [b][j][d] (j = i+1), v -> bf16 V^T [b][d][j]
__global__ __launch_bounds__(256) void relayout_kv(
    const float* __restrict__ tmpkv, unsigned short* __restrict__ kb,
    unsigned short* __restrict__ vbT) {
  size_t e = (size_t)blockIdx.x * 256 + threadIdx.x;  // float4 index
  int m = (int)(e >> 5), c4 = (int)(e & 31);
  int b = m >> 11, i = m & 2047;
  float4 v = ((const float4*)tmpkv)[e];
  if (c4 < 16) {
    ushort4 o;
    o.x = f2bf(v.x); o.y = f2bf(v.y); o.z = f2bf(v.z); o.w = f2bf(v.w);
    ((ushort4*)kb)[((size_t)b * NKROWS + (i + 1)) * 16 + c4] = o;
  } else {
    int d = (c4 - 16) * 4;
    size_t base = (size_t)b * DHEAD * NKP + (size_t)d * NKP + (i + 1);
    vbT[base]           = f2bf(v.x);
    vbT[base + NKP]     = f2bf(v.y);
    vbT[base + 2 * NKP] = f2bf(v.z);
    vbT[base + 3 * NKP] = f2bf(v.w);
  }
}

__global__ void fill_null(const float* __restrict__ null_kv,
                          unsigned short* __restrict__ kb,
                          unsigned short* __restrict__ vbT) {
  int b = blockIdx.x, d = threadIdx.x;  // 2 blocks x 64
  kb[(size_t)b * NKROWS * DHEAD + d] = f2bf(null_kv[d]);
  vbT[(size_t)b * DHEAD * NKP + (size_t)d * NKP] = f2bf(null_kv[DHEAD + d]);
}

// pos-bias pre: out[r][c] = (r - (SEQ-1)) * w0[c] + b0[c]
__global__ __launch_bounds__(256) void posbias_pre(
    const float* __restrict__ w0, const float* __restrict__ b0,
    float* __restrict__ out) {
  int r = blockIdx.x, t = threadIdx.x;
  float p = (float)(r - (SEQ - 1));
  float4 w = ((const float4*)w0)[t];
  float4 bb = ((const float4*)b0)[t];
  float4 o;
  o.x = p * w.x + bb.x; o.y = p * w.y + bb.y;
  o.z = p * w.z + bb.z; o.w = p * w.w + bb.w;
  ((float4*)(out + (size_t)r * DIMM))[t] = o;
}

// h2: bias_tab[r][col] = h1[r][:] . w2[:][col] + b2[col]
__global__ __launch_bounds__(256) void h2_kernel(
    const float* __restrict__ h1, const float* __restrict__ w2,
    const float* __restrict__ b2, float* __restrict__ bias_tab) {
  int r = blockIdx.x, t = threadIdx.x;
  int col = t & 15, seg = t >> 4;
  const float* hr = h1 + (size_t)r * DIMM;
  float acc = 0.f;
  for (int k = seg * 64; k < seg * 64 + 64; ++k)
    acc += hr[k] * w2[(size_t)k * NHEADS + col];
  __shared__ float p[16][16];
  p[seg][col] = acc;
  __syncthreads();
  if (t < 16) {
    float s = 0.f;
#pragma unroll
    for (int q = 0; q < 16; q++) s += p[q][t];
    bias_tab[(size_t)r * NHEADS + t] = s + b2[t];
  }
}

// ---------------------------------------------------------------------------
// Flash attention, MFMA bf16.  Block = 4 waves = 64 Q rows of one (b,h).
// Wave w owns rows [qt*64 + w*16, +16).  K tiles of 64 keys, causal prefix.
// C/D frag layout (m89): col = lane&15, row = (lane>>4)*4 + reg.
// A frag: row = lane&15, k = (lane>>4)*8 + j.  B frag: col = lane&15, same k.
// ---------------------------------------------------------------------------
__global__ __launch_bounds__(256) void flash_attn(
    const unsigned short* __restrict__ qb, const unsigned short* __restrict__ kb,
    const unsigned short* __restrict__ vbT, const float* __restrict__ bias_tab,
    const float* __restrict__ null_bias, float* __restrict__ outb) {
  const int qt = blockIdx.x, h = blockIdx.y, b = blockIdx.z;
  const int w = threadIdx.x >> 6, lane = threadIdx.x & 63;
  const int lo = lane & 15, hi = lane >> 4;
  const int q0 = qt * 64, r0 = w * 16;

  __shared__ unsigned short plds[4][16][72];  // +8 pad: 2-way banks only

  const unsigned short* qrow =
      qb + (size_t)((b * NHEADS + h) * SEQ + q0 + r0 + lo) * DHEAD;
  bf16x8 qa0 = *(const bf16x8*)(qrow + hi * 8);
  bf16x8 qa1 = *(const bf16x8*)(qrow + 32 + hi * 8);

  const unsigned short* Kb = kb + (size_t)b * NKROWS * DHEAD;
  const unsigned short* Vb = vbT + (size_t)b * DHEAD * NKP;
  const float nb = null_bias[h];

  f32x4 o[4];
  float m_r[4], l_r[4];
#pragma unroll
  for (int nf = 0; nf < 4; ++nf) o[nf] = f32x4{0.f, 0.f, 0.f, 0.f};
#pragma unroll
  for (int r = 0; r < 4; ++r) { m_r[r] = -3.0e38f; l_r[r] = 0.f; }

  const int nkt = qt + 2;  // keys up to q0+64 inclusive
  for (int kt = 0; kt < nkt; ++kt) {
    const int j0 = kt * 64;
    // ---- S = Q @ K^T (16 x 64 per wave) ----
    f32x4 s[4];
#pragma unroll
    for (int nf = 0; nf < 4; ++nf) {
      const unsigned short* krow = Kb + (size_t)(j0 + nf * 16 + lo) * DHEAD;
      bf16x8 k0 = *(const bf16x8*)(krow + hi * 8);
      bf16x8 k1 = *(const bf16x8*)(krow + 32 + hi * 8);
      f32x4 acc = f32x4{0.f, 0.f, 0.f, 0.f};
      acc = __builtin_amdgcn_mfma_f32_16x16x32_bf16(qa0, k0, acc, 0, 0, 0);
      acc = __builtin_amdgcn_mfma_f32_16x16x32_bf16(qa1, k1, acc, 0, 0, 0);
      s[nf] = acc;
    }
    // ---- bias + causal mask ----
#pragma unroll
    for (int nf = 0; nf < 4; ++nf) {
      const int col = j0 + nf * 16 + lo;  // key index (0 = null)
#pragma unroll
      for (int r = 0; r < 4; ++r) {
        const int row = q0 + r0 + hi * 4 + r;  // query index
        float bias = (col == 0)
                         ? nb
                         : bias_tab[(size_t)(row - col + SEQ) * NHEADS + h];
        s[nf][r] = (col <= row + 1) ? (s[nf][r] + bias) : -3.0e38f;
      }
    }
    // ---- online softmax (row stats; reduce across 16-lane col groups) ----
    float tm[4];
#pragma unroll
    for (int r = 0; r < 4; ++r)
      tm[r] = fmaxf(fmaxf(s[0][r], s[1][r]), fmaxf(s[2][r], s[3][r]));
#pragma unroll
    for (int off = 1; off < 16; off <<= 1)
#pragma unroll
      for (int r = 0; r < 4; ++r)
        tm[r] = fmaxf(tm[r], __shfl_xor(tm[r], off));
    float sco[4], ls[4] = {0.f, 0.f, 0.f, 0.f};
#pragma unroll
    for (int r = 0; r < 4; ++r) {
      float mn = fmaxf(m_r[r], tm[r]);
      sco[r] = __expf(m_r[r] - mn);
      m_r[r] = mn;
    }
#pragma unroll
    for (int nf = 0; nf < 4; ++nf)
#pragma unroll
      for (int r = 0; r < 4; ++r) {
        float p = __expf(s[nf][r] - m_r[r]);  // masked -> 0
        s[nf][r] = p;
        ls[r] += p;
      }
#pragma unroll
    for (int off = 1; off < 16; off <<= 1)
#pragma unroll
      for (int r = 0; r < 4; ++r) ls[r] += __shfl_xor(ls[r], off);
#pragma unroll
    for (int r = 0; r < 4; ++r) l_r[r] = l_r[r] * sco[r] + ls[r];
#pragma unroll
    for (int nf = 0; nf < 4; ++nf)
#pragma unroll
      for (int r = 0; r < 4; ++r) o[nf][r] *= sco[r];
    // ---- P (C-layout) -> LDS -> A-frags ----
#pragma unroll
    for (int nf = 0; nf < 4; ++nf)
#pragma unroll
      for (int r = 0; r < 4; ++r)
        plds[w][hi * 4 + r][nf * 16 + lo] = f2bf(s[nf][r]);
    bf16x8 pa0 = *(const bf16x8*)&plds[w][lo][hi * 8];
    bf16x8 pa1 = *(const bf16x8*)&plds[w][lo][32 + hi * 8];
    // ---- O += P @ V ----
#pragma unroll
    for (int nf = 0; nf < 4; ++nf) {
      const unsigned short* vrow = Vb + (size_t)(nf * 16 + lo) * NKP + j0;
      bf16x8 v0 = *(const bf16x8*)(vrow + hi * 8);
      bf16x8 v1 = *(const bf16x8*)(vrow + 32 + hi * 8);
      o[nf] = __builtin_amdgcn_mfma_f32_16x16x32_bf16(pa0, v0, o[nf], 0, 0, 0);
      o[nf] = __builtin_amdgcn_mfma_f32_16x16x32_bf16(pa1, v1, o[nf], 0, 0, 0);
    }
  }
  // ---- write out [b][i][h*64+d], normalized ----
#pragma unroll
  for (int nf = 0; nf < 4; ++nf)
#pragma unroll
    for (int r = 0; r < 4; ++r) {
      const int row = q0 + r0 + hi * 4 + r;
      outb[(size_t)(b * SEQ + row) * DIMM + h * DHEAD + nf * 16 + lo] =
          o[nf][r] / l_r[r];
    }
}

// ---------------------------------------------------------------------------
extern "C" void kernel_launch(void* const* d_in, const int* in_sizes, int n_in,
                              void* d_out, int out_size, void* d_ws,
                              size_t ws_size, hipStream_t stream) {
  const float* x         = (const float*)d_in[0];
  const float* ln_g      = (const float*)d_in[1];
  const float* ln_b      = (const float*)d_in[2];
  const float* Wq        = (const float*)d_in[3];
  const float* Wkv       = (const float*)d_in[4];
  const float* null_kv   = (const float*)d_in[5];
  const float* null_bias = (const float*)d_in[6];
  const float* pb_w0     = (const float*)d_in[7];
  const float* pb_b0     = (const float*)d_in[8];
  const float* pb_ln0_g  = (const float*)d_in[9];
  const float* pb_ln0_b  = (const float*)d_in[10];
  const float* pb_w1     = (const float*)d_in[11];
  const float* pb_b1     = (const float*)d_in[12];
  const float* pb_ln1_g  = (const float*)d_in[13];
  const float* pb_ln1_b  = (const float*)d_in[14];
  const float* pb_w2     = (const float*)d_in[15];
  const float* pb_b2     = (const float*)d_in[16];
  const float* Wo        = (const float*)d_in[17];
  const float* out_ln_g  = (const float*)d_in[18];
  const float* out_ln_b  = (const float*)d_in[19];
  float* out = (float*)d_out;

  float* ws = (float*)d_ws;
  float* xn        = ws;                  // 4096*1024 f32
  float* tmpA      = ws + 4194304;        // 4096*1024 f32 (q-pre/h1-pre/attn-out)
  float* qslot     = ws + 8388608;        // bf16 q first, later f32 final-pre
  float* h0        = ws + 12582912;       // 4095*1024 f32
  float* tmpKV     = ws + 16777216;       // 4096*128 f32
  unsigned short* kbu  = (unsigned short*)(ws + 17301504);  // 2*2112*64 bf16
  unsigned short* vbTu = (unsigned short*)(ws + 17436672);  // 2*64*2112 bf16
  float* bias_tab  = ws + 17571840;       // 4095*16 f32

  // zero padded K / V^T buffers (padding rows feed masked MFMA lanes)
  hipMemsetAsync((void*)kbu, 0, (size_t)2 * NKROWS * DHEAD * 2 * 2, stream);

  // 1. xn = LN(x)
  ln_kernel<<<ROWS, 256, 0, stream>>>(x, nullptr, ln_g, ln_b, xn, 0);
  // 2. q = xn @ Wq -> bf16 relayout (scale folded)
  gemm_f32<<<dim3(DIMM / 64, ROWS / 64), 256, 0, stream>>>(xn, Wq, tmpA, ROWS,
                                                           DIMM, DIMM);
  relayout_q<<<4096, 256, 0, stream>>>(tmpA, (unsigned short*)qslot);
  // 3. kv = xn @ Wkv ; split + null prepend (bf16, V transposed)
  gemm_f32<<<dim3(2, ROWS / 64), 256, 0, stream>>>(xn, Wkv, tmpKV, ROWS, 128,
                                                   DIMM);
  relayout_kv<<<512, 256, 0, stream>>>(tmpKV, kbu, vbTu);
  fill_null<<<2, 64, 0, stream>>>(null_kv, kbu, vbTu);
  // 4. dynamic pos-bias MLP -> bias_tab
  posbias_pre<<<PBROWS, 256, 0, stream>>>(pb_w0, pb_b0, h0);
  ln_kernel<<<PBROWS, 256, 0, stream>>>(h0, nullptr, pb_ln0_g, pb_ln0_b, h0, 1);
  gemm_f32<<<dim3(DIMM / 64, (PBROWS + 63) / 64), 256, 0, stream>>>(
      h0, pb_w1, tmpA, PBROWS, DIMM, DIMM);
  ln_kernel<<<PBROWS, 256, 0, stream>>>(tmpA, pb_b1, pb_ln1_g, pb_ln1_b, h0, 1);
  h2_kernel<<<PBROWS, 256, 0, stream>>>(h0, pb_w2, pb_b2, bias_tab);
  // 5. flash attention -> tmpA (b, n, INNER layout)
  flash_attn<<<dim3(SEQ / 64, NHEADS, BATCH), 256, 0, stream>>>(
      (const unsigned short*)qslot, kbu, vbTu, bias_tab, null_bias, tmpA);
  // 6. out = LN(attn_out @ Wo)
  gemm_f32<<<dim3(DIMM / 64, ROWS / 64), 256, 0, stream>>>(tmpA, Wo, qslot,
                                                           ROWS, DIMM, DIMM);
  ln_kernel<<<ROWS, 256, 0, stream>>>(qslot, nullptr, out_ln_g, out_ln_b, out,
                                      0);
}

// Round 3
// 501.863 us; speedup vs baseline: 10.1285x; 2.6812x over previous
//
#include <hip/hip_runtime.h>
#include <hip/hip_bf16.h>
#include <math.h>

#define DIMM   1024
#define NHEADS 16
#define DHEAD  64
#define BATCH  2
#define SEQ    2048
#define NKEYS  (SEQ + 1)      // 2049 (null + seq)
#define NKROWS 2112           // padded K rows
#define NKP    2112           // padded key count for V^T inner dim
#define PBROWS (2 * SEQ - 1)  // 4095
#define ROWS   (BATCH * SEQ)  // 4096

using bf16x8 = __attribute__((ext_vector_type(8))) short;
using f32x4  = __attribute__((ext_vector_type(4))) float;
typedef unsigned int u32;
typedef unsigned short u16;

__device__ __forceinline__ u16 f2bf(float f) {
  __hip_bfloat16 h = __float2bfloat16(f);
  return __builtin_bit_cast(u16, h);
}
__device__ __forceinline__ float bf2f(u16 u) {
  u32 x = ((u32)u) << 16;
  return __builtin_bit_cast(float, x);
}
__device__ __forceinline__ void gl_lds16(const void* g, void* l) {
  __builtin_amdgcn_global_load_lds(
      (const __attribute__((address_space(1))) u32*)g,
      (__attribute__((address_space(3))) u32*)l, 16, 0, 0);
}

// ---------------------------------------------------------------------------
// LayerNorm over last dim (=1024).  obf16: output bf16 instead of f32.
// ---------------------------------------------------------------------------
__global__ __launch_bounds__(256) void ln_kernel(
    const float* __restrict__ in, const float* __restrict__ addb,
    const float* __restrict__ g, const float* __restrict__ bvec,
    void* __restrict__ outv, int silu, int obf16) {
  int row = blockIdx.x;
  int t = threadIdx.x;
  float4 x = ((const float4*)(in + (size_t)row * DIMM))[t];
  if (addb) {
    float4 a = ((const float4*)addb)[t];
    x.x += a.x; x.y += a.y; x.z += a.z; x.w += a.w;
  }
  float s  = x.x + x.y + x.z + x.w;
  float ss = x.x * x.x + x.y * x.y + x.z * x.z + x.w * x.w;
#pragma unroll
  for (int off = 32; off > 0; off >>= 1) {
    s  += __shfl_down(s, off);
    ss += __shfl_down(ss, off);
  }
  __shared__ float rs[4], rss[4];
  int wv = t >> 6, lane = t & 63;
  if (lane == 0) { rs[wv] = s; rss[wv] = ss; }
  __syncthreads();
  float S  = rs[0] + rs[1] + rs[2] + rs[3];
  float SS = rss[0] + rss[1] + rss[2] + rss[3];
  float mu  = S * (1.0f / DIMM);
  float var = SS * (1.0f / DIMM) - mu * mu;
  float inv = rsqrtf(var + 1e-5f);
  float4 gv = ((const float4*)g)[t];
  float4 bv = ((const float4*)bvec)[t];
  float4 o;
  o.x = (x.x - mu) * inv * gv.x + bv.x;
  o.y = (x.y - mu) * inv * gv.y + bv.y;
  o.z = (x.z - mu) * inv * gv.z + bv.z;
  o.w = (x.w - mu) * inv * gv.w + bv.w;
  if (silu) {
    o.x = o.x / (1.f + expf(-o.x));
    o.y = o.y / (1.f + expf(-o.y));
    o.z = o.z / (1.f + expf(-o.z));
    o.w = o.w / (1.f + expf(-o.w));
  }
  if (obf16) {
    ushort4 ob;
    ob.x = f2bf(o.x); ob.y = f2bf(o.y); ob.z = f2bf(o.z); ob.w = f2bf(o.w);
    ((ushort4*)((u16*)outv + (size_t)row * DIMM))[t] = ob;
  } else {
    ((float4*)((float*)outv + (size_t)row * DIMM))[t] = o;
  }
}

// ---------------------------------------------------------------------------
// Weight convert+transpose: W f32 [K=1024][N] -> WT bf16 [rowOff+N][1024]
// ---------------------------------------------------------------------------
__global__ __launch_bounds__(256) void conv_wT(
    const float* __restrict__ W, u16* __restrict__ WT, int N, int rowOff) {
  __shared__ float tile[32][33];
  const int n0 = blockIdx.x * 32, k0 = blockIdx.y * 32;
  const int tc = threadIdx.x & 31, tr = threadIdx.x >> 5;  // tr 0..7
#pragma unroll
  for (int i = 0; i < 4; ++i)
    tile[tr + i * 8][tc] = W[(size_t)(k0 + tr + i * 8) * N + n0 + tc];
  __syncthreads();
#pragma unroll
  for (int i = 0; i < 4; ++i) {
    int r = tr + i * 8;
    WT[(size_t)(rowOff + n0 + r) * 1024 + k0 + tc] = f2bf(tile[tc][r]);
  }
}

// ---------------------------------------------------------------------------
// bf16 MFMA GEMM (m97 structure): A bf16 [M][K], BT bf16 [N][K], C f32 [M][N]
// 128x128 tile, BK=32, 4 waves (2x2), global_load_lds width 16.
// ---------------------------------------------------------------------------
__global__ __launch_bounds__(256) void gemm_bf16(
    const u16* __restrict__ A, const u16* __restrict__ BT,
    float* __restrict__ C, int M, int N, int K) {
  __shared__ u16 As[128 * 32];
  __shared__ u16 Bs[128 * 32];
  const int w = threadIdx.x >> 6, lane = threadIdx.x & 63;
  const int lo = lane & 15, hi = lane >> 4;
  const int wr = w >> 1, wc = w & 1;
  const int row0 = blockIdx.y * 128, col0 = blockIdx.x * 128;
  const int srow = lane >> 2;       // 0..15
  const int scol = (lane & 3) * 8;  // 0,8,16,24
  f32x4 acc[4][4];
#pragma unroll
  for (int m = 0; m < 4; ++m)
#pragma unroll
    for (int n = 0; n < 4; ++n) acc[m][n] = f32x4{0.f, 0.f, 0.f, 0.f};
  for (int k0 = 0; k0 < K; k0 += 32) {
#pragma unroll
    for (int c = 0; c < 2; ++c) {
      const int base = 32 * w + c * 16;  // wave-uniform chunk base row
      gl_lds16(A + (size_t)(row0 + base + srow) * K + k0 + scol,
               &As[base * 32]);
      gl_lds16(BT + (size_t)(col0 + base + srow) * K + k0 + scol,
               &Bs[base * 32]);
    }
    __syncthreads();  // drains vmcnt -> LDS valid
    bf16x8 af[4], bg[4];
#pragma unroll
    for (int m = 0; m < 4; ++m)
      af[m] = *(const bf16x8*)&As[(wr * 64 + m * 16 + lo) * 32 + hi * 8];
#pragma unroll
    for (int n = 0; n < 4; ++n)
      bg[n] = *(const bf16x8*)&Bs[(wc * 64 + n * 16 + lo) * 32 + hi * 8];
#pragma unroll
    for (int m = 0; m < 4; ++m)
#pragma unroll
      for (int n = 0; n < 4; ++n)
        acc[m][n] = __builtin_amdgcn_mfma_f32_16x16x32_bf16(af[m], bg[n],
                                                            acc[m][n], 0, 0, 0);
    __syncthreads();  // protect LDS before next stage
  }
#pragma unroll
  for (int m = 0; m < 4; ++m)
#pragma unroll
    for (int r = 0; r < 4; ++r) {
      const int row = row0 + wr * 64 + m * 16 + hi * 4 + r;
      if (row < M) {
#pragma unroll
        for (int n = 0; n < 4; ++n)
          C[(size_t)row * N + col0 + wc * 64 + n * 16 + lo] = acc[m][n][r];
      }
    }
}

// ---------------------------------------------------------------------------
// q relayout from tmpQKV (stride 1152, cols 0..1023) -> bf16 [b][h][i][d] /8
// ---------------------------------------------------------------------------
__global__ __launch_bounds__(256) void relayout_q(
    const float* __restrict__ tmp, u16* __restrict__ qb) {
  size_t e = (size_t)blockIdx.x * 256 + threadIdx.x;  // float4 index
  int m = (int)(e >> 8), c4 = (int)(e & 255);
  int b = m >> 11, i = m & 2047;
  int h = c4 >> 4, d4 = c4 & 15;
  float4 v = ((const float4*)(tmp + (size_t)m * 1152))[c4];
  const float sc = 0.125f;
  ushort4 o;
  o.x = f2bf(v.x * sc); o.y = f2bf(v.y * sc);
  o.z = f2bf(v.z * sc); o.w = f2bf(v.w * sc);
  ((ushort4*)qb)[((size_t)(b * NHEADS + h) * SEQ + i) * 16 + d4] = o;
}

// kv relayout from tmpQKV cols 1024..1151 -> k bf16 [b][j][d], v^T [b][d][j]
__global__ __launch_bounds__(256) void relayout_kv(
    const float* __restrict__ tmp, u16* __restrict__ kb, u16* __restrict__ vbT) {
  size_t e = (size_t)blockIdx.x * 256 + threadIdx.x;  // float4 index
  int m = (int)(e >> 5), c4 = (int)(e & 31);
  int b = m >> 11, i = m & 2047;
  float4 v = ((const float4*)(tmp + (size_t)m * 1152 + 1024))[c4];
  if (c4 < 16) {
    ushort4 o;
    o.x = f2bf(v.x); o.y = f2bf(v.y); o.z = f2bf(v.z); o.w = f2bf(v.w);
    ((ushort4*)kb)[((size_t)b * NKROWS + (i + 1)) * 16 + c4] = o;
  } else {
    int d = (c4 - 16) * 4;
    size_t base = (size_t)b * DHEAD * NKP + (size_t)d * NKP + (i + 1);
    vbT[base]           = f2bf(v.x);
    vbT[base + NKP]     = f2bf(v.y);
    vbT[base + 2 * NKP] = f2bf(v.z);
    vbT[base + 3 * NKP] = f2bf(v.w);
  }
}

__global__ void fill_null(const float* __restrict__ null_kv,
                          u16* __restrict__ kb, u16* __restrict__ vbT) {
  int b = blockIdx.x, d = threadIdx.x;
  kb[(size_t)b * NKROWS * DHEAD + d] = f2bf(null_kv[d]);
  vbT[(size_t)b * DHEAD * NKP + (size_t)d * NKP] = f2bf(null_kv[DHEAD + d]);
}

// pos-bias pre: out[r][c] = (r - (SEQ-1)) * w0[c] + b0[c]
__global__ __launch_bounds__(256) void posbias_pre(
    const float* __restrict__ w0, const float* __restrict__ b0,
    float* __restrict__ out) {
  int r = blockIdx.x, t = threadIdx.x;
  float p = (float)(r - (SEQ - 1));
  float4 w = ((const float4*)w0)[t];
  float4 bb = ((const float4*)b0)[t];
  float4 o;
  o.x = p * w.x + bb.x; o.y = p * w.y + bb.y;
  o.z = p * w.z + bb.z; o.w = p * w.w + bb.w;
  ((float4*)(out + (size_t)r * DIMM))[t] = o;
}

// h2: bias_tabT[h][r] = h1[r][:] . w2[:][h] + b2[h]   (transposed table)
__global__ __launch_bounds__(256) void h2_kernel(
    const u16* __restrict__ h1, const float* __restrict__ w2,
    const float* __restrict__ b2, float* __restrict__ bias_tabT) {
  int r = blockIdx.x, t = threadIdx.x;
  int col = t & 15, seg = t >> 4;
  const u16* hr = h1 + (size_t)r * DIMM;
  float acc = 0.f;
  for (int k = seg * 64; k < seg * 64 + 64; ++k)
    acc += bf2f(hr[k]) * w2[(size_t)k * NHEADS + col];
  __shared__ float p[16][16];
  p[seg][col] = acc;
  __syncthreads();
  if (t < 16) {
    float s = 0.f;
#pragma unroll
    for (int q = 0; q < 16; q++) s += p[q][t];
    bias_tabT[(size_t)t * 4096 + r] = s + b2[t];
  }
}

// ---------------------------------------------------------------------------
// Flash attention, MFMA bf16.  Block = 4 waves = 64 Q rows of one (b,h).
// qt descending for load balance; bias_tabT[h][pos] coalesced gather.
// ---------------------------------------------------------------------------
__global__ __launch_bounds__(256) void flash_attn(
    const u16* __restrict__ qb, const u16* __restrict__ kb,
    const u16* __restrict__ vbT, const float* __restrict__ bias_tabT,
    const float* __restrict__ null_bias, u16* __restrict__ outb) {
  const int qt = gridDim.x - 1 - blockIdx.x;  // heavy blocks first
  const int h = blockIdx.y, b = blockIdx.z;
  const int w = threadIdx.x >> 6, lane = threadIdx.x & 63;
  const int lo = lane & 15, hi = lane >> 4;
  const int q0 = qt * 64, r0 = w * 16;

  __shared__ u16 plds[4][16][72];  // +8 pad

  const u16* qrow = qb + (size_t)((b * NHEADS + h) * SEQ + q0 + r0 + lo) * DHEAD;
  bf16x8 qa0 = *(const bf16x8*)(qrow + hi * 8);
  bf16x8 qa1 = *(const bf16x8*)(qrow + 32 + hi * 8);

  const u16* Kb = kb + (size_t)b * NKROWS * DHEAD;
  const u16* Vb = vbT + (size_t)b * DHEAD * NKP;
  const float* bt = bias_tabT + (size_t)h * 4096;
  const float nb = null_bias[h];

  f32x4 o[4];
  float m_r[4], l_r[4];
#pragma unroll
  for (int nf = 0; nf < 4; ++nf) o[nf] = f32x4{0.f, 0.f, 0.f, 0.f};
#pragma unroll
  for (int r = 0; r < 4; ++r) { m_r[r] = -3.0e38f; l_r[r] = 0.f; }

  const int nkt = qt + 2;
  for (int kt = 0; kt < nkt; ++kt) {
    const int j0 = kt * 64;
    // ---- prefetch bias (coalesced: lanes read consecutive floats) ----
    float bias[4][4];
#pragma unroll
    for (int nf = 0; nf < 4; ++nf) {
      const int col = j0 + nf * 16 + lo;
#pragma unroll
      for (int r = 0; r < 4; ++r) {
        const int row = q0 + r0 + hi * 4 + r;
        bias[nf][r] = (col == 0) ? nb : bt[row - col + SEQ];
      }
    }
    // ---- S = Q @ K^T ----
    f32x4 s[4];
#pragma unroll
    for (int nf = 0; nf < 4; ++nf) {
      const u16* krow = Kb + (size_t)(j0 + nf * 16 + lo) * DHEAD;
      bf16x8 k0 = *(const bf16x8*)(krow + hi * 8);
      bf16x8 k1 = *(const bf16x8*)(krow + 32 + hi * 8);
      f32x4 acc = f32x4{0.f, 0.f, 0.f, 0.f};
      acc = __builtin_amdgcn_mfma_f32_16x16x32_bf16(qa0, k0, acc, 0, 0, 0);
      acc = __builtin_amdgcn_mfma_f32_16x16x32_bf16(qa1, k1, acc, 0, 0, 0);
      s[nf] = acc;
    }
    // ---- bias + causal mask ----
#pragma unroll
    for (int nf = 0; nf < 4; ++nf) {
      const int col = j0 + nf * 16 + lo;
#pragma unroll
      for (int r = 0; r < 4; ++r) {
        const int row = q0 + r0 + hi * 4 + r;
        s[nf][r] = (col <= row + 1) ? (s[nf][r] + bias[nf][r]) : -3.0e38f;
      }
    }
    // ---- online softmax ----
    float tm[4];
#pragma unroll
    for (int r = 0; r < 4; ++r)
      tm[r] = fmaxf(fmaxf(s[0][r], s[1][r]), fmaxf(s[2][r], s[3][r]));
#pragma unroll
    for (int off = 1; off < 16; off <<= 1)
#pragma unroll
      for (int r = 0; r < 4; ++r)
        tm[r] = fmaxf(tm[r], __shfl_xor(tm[r], off));
    float sco[4], ls[4] = {0.f, 0.f, 0.f, 0.f};
#pragma unroll
    for (int r = 0; r < 4; ++r) {
      float mn = fmaxf(m_r[r], tm[r]);
      sco[r] = __expf(m_r[r] - mn);
      m_r[r] = mn;
    }
#pragma unroll
    for (int nf = 0; nf < 4; ++nf)
#pragma unroll
      for (int r = 0; r < 4; ++r) {
        float p = __expf(s[nf][r] - m_r[r]);
        s[nf][r] = p;
        ls[r] += p;
      }
#pragma unroll
    for (int off = 1; off < 16; off <<= 1)
#pragma unroll
      for (int r = 0; r < 4; ++r) ls[r] += __shfl_xor(ls[r], off);
#pragma unroll
    for (int r = 0; r < 4; ++r) l_r[r] = l_r[r] * sco[r] + ls[r];
#pragma unroll
    for (int nf = 0; nf < 4; ++nf)
#pragma unroll
      for (int r = 0; r < 4; ++r) o[nf][r] *= sco[r];
    // ---- P -> LDS -> A-frags ----
#pragma unroll
    for (int nf = 0; nf < 4; ++nf)
#pragma unroll
      for (int r = 0; r < 4; ++r)
        plds[w][hi * 4 + r][nf * 16 + lo] = f2bf(s[nf][r]);
    bf16x8 pa0 = *(const bf16x8*)&plds[w][lo][hi * 8];
    bf16x8 pa1 = *(const bf16x8*)&plds[w][lo][32 + hi * 8];
    // ---- O += P @ V ----
#pragma unroll
    for (int nf = 0; nf < 4; ++nf) {
      const u16* vrow = Vb + (size_t)(nf * 16 + lo) * NKP + j0;
      bf16x8 v0 = *(const bf16x8*)(vrow + hi * 8);
      bf16x8 v1 = *(const bf16x8*)(vrow + 32 + hi * 8);
      o[nf] = __builtin_amdgcn_mfma_f32_16x16x32_bf16(pa0, v0, o[nf], 0, 0, 0);
      o[nf] = __builtin_amdgcn_mfma_f32_16x16x32_bf16(pa1, v1, o[nf], 0, 0, 0);
    }
  }
  // ---- write bf16 out [b][i][h*64+d] ----
#pragma unroll
  for (int nf = 0; nf < 4; ++nf)
#pragma unroll
    for (int r = 0; r < 4; ++r) {
      const int row = q0 + r0 + hi * 4 + r;
      outb[(size_t)(b * SEQ + row) * DIMM + h * DHEAD + nf * 16 + lo] =
          f2bf(o[nf][r] / l_r[r]);
    }
}

// ---------------------------------------------------------------------------
extern "C" void kernel_launch(void* const* d_in, const int* in_sizes, int n_in,
                              void* d_out, int out_size, void* d_ws,
                              size_t ws_size, hipStream_t stream) {
  const float* x         = (const float*)d_in[0];
  const float* ln_g      = (const float*)d_in[1];
  const float* ln_b      = (const float*)d_in[2];
  const float* Wq        = (const float*)d_in[3];
  const float* Wkv       = (const float*)d_in[4];
  const float* null_kv   = (const float*)d_in[5];
  const float* null_bias = (const float*)d_in[6];
  const float* pb_w0     = (const float*)d_in[7];
  const float* pb_b0     = (const float*)d_in[8];
  const float* pb_ln0_g  = (const float*)d_in[9];
  const float* pb_ln0_b  = (const float*)d_in[10];
  const float* pb_w1     = (const float*)d_in[11];
  const float* pb_b1     = (const float*)d_in[12];
  const float* pb_ln1_g  = (const float*)d_in[13];
  const float* pb_ln1_b  = (const float*)d_in[14];
  const float* pb_w2     = (const float*)d_in[15];
  const float* pb_b2     = (const float*)d_in[16];
  const float* Wo        = (const float*)d_in[17];
  const float* out_ln_g  = (const float*)d_in[18];
  const float* out_ln_b  = (const float*)d_in[19];
  float* out = (float*)d_out;

  char* ws = (char*)d_ws;
  // Region A: f32 4096x1152 (tmpQKV -> gemm3 out -> gemm4 out)
  float* regA      = (float*)(ws);                      // 18,874,368 B
  // Region B: f32 4095x1024 (pb0) -> later h1_bf
  float* pb0       = (float*)(ws + 18874368);           // 16,777,216 B
  u16*   h1_bf     = (u16*)(ws + 18874368);
  // Region C: bf16 4096x1024 (xn_bf -> h0_bf -> attn_bf)
  u16*   regC      = (u16*)(ws + 35651584);             // 8,388,608 B
  // Region D: qb bf16
  u16*   qb        = (u16*)(ws + 44040192);             // 8,388,608 B
  // Region E: kb + vbT bf16 (padded)
  u16*   kb        = (u16*)(ws + 52428800);             // 540,672 B
  u16*   vbT       = (u16*)(ws + 52969472);             // 540,672 B
  // Region F: weights bf16 transposed
  u16*   wqkvT     = (u16*)(ws + 53510144);             // 1152x1024x2
  u16*   w1T       = (u16*)(ws + 55869440);             // 1024x1024x2
  u16*   woT       = (u16*)(ws + 57966592);             // 1024x1024x2
  // Region G: bias_tabT f32 [16][4096]
  float* bias_tabT = (float*)(ws + 60063744);           // 262,144 B

  // zero K/V padding (single memset over region E)
  hipMemsetAsync((void*)kb, 0, 1081344, stream);

  // weight conversions (transpose to [N][K] bf16)
  conv_wT<<<dim3(32, 32), 256, 0, stream>>>(Wq, wqkvT, 1024, 0);
  conv_wT<<<dim3(4, 32), 256, 0, stream>>>(Wkv, wqkvT, 128, 1024);
  conv_wT<<<dim3(32, 32), 256, 0, stream>>>(pb_w1, w1T, 1024, 0);
  conv_wT<<<dim3(32, 32), 256, 0, stream>>>(Wo, woT, 1024, 0);

  // 1. xn = LN(x) -> bf16
  ln_kernel<<<ROWS, 256, 0, stream>>>(x, nullptr, ln_g, ln_b, regC, 0, 1);
  // 2. fused q|kv GEMM: [4096x1024] @ [1024x1152] -> regA f32
  gemm_bf16<<<dim3(9, 32), 256, 0, stream>>>(regC, wqkvT, regA, ROWS, 1152,
                                             1024);
  relayout_q<<<4096, 256, 0, stream>>>(regA, qb);
  relayout_kv<<<512, 256, 0, stream>>>(regA, kb, vbT);
  fill_null<<<2, 64, 0, stream>>>(null_kv, kb, vbT);
  // 3. pos-bias MLP
  posbias_pre<<<PBROWS, 256, 0, stream>>>(pb_w0, pb_b0, pb0);
  ln_kernel<<<PBROWS, 256, 0, stream>>>(pb0, nullptr, pb_ln0_g, pb_ln0_b, regC,
                                        1, 1);  // h0_bf in regC
  gemm_bf16<<<dim3(8, 32), 256, 0, stream>>>(regC, w1T, regA, PBROWS, 1024,
                                             1024);
  ln_kernel<<<PBROWS, 256, 0, stream>>>(regA, pb_b1, pb_ln1_g, pb_ln1_b, h1_bf,
                                        1, 1);
  h2_kernel<<<PBROWS, 256, 0, stream>>>(h1_bf, pb_w2, pb_b2, bias_tabT);
  // 4. flash attention -> attn_bf (regC)
  flash_attn<<<dim3(SEQ / 64, NHEADS, BATCH), 256, 0, stream>>>(
      qb, kb, vbT, bias_tabT, null_bias, regC);
  // 5. out = LN(attn @ Wo)
  gemm_bf16<<<dim3(8, 32), 256, 0, stream>>>(regC, woT, regA, ROWS, 1024, 1024);
  ln_kernel<<<ROWS, 256, 0, stream>>>(regA, nullptr, out_ln_g, out_ln_b, out, 0,
                                      0);
}

// Round 4
// 499.701 us; speedup vs baseline: 10.1723x; 1.0043x over previous
//
#include <hip/hip_runtime.h>
#include <hip/hip_bf16.h>
#include <math.h>

#define DIMM   1024
#define NHEADS 16
#define DHEAD  64
#define BATCH  2
#define SEQ    2048
#define NKEYS  (SEQ + 1)      // 2049 (null + seq)
#define NKROWS 2112           // padded K rows
#define NKP    2112           // padded key count for V^T inner dim
#define PBROWS (2 * SEQ - 1)  // 4095
#define ROWS   (BATCH * SEQ)  // 4096

using bf16x8 = __attribute__((ext_vector_type(8))) short;
using f32x4  = __attribute__((ext_vector_type(4))) float;
typedef unsigned int u32;
typedef unsigned short u16;

__device__ __forceinline__ u16 f2bf(float f) {
  __hip_bfloat16 h = __float2bfloat16(f);
  return __builtin_bit_cast(u16, h);
}
__device__ __forceinline__ float bf2f(u16 u) {
  u32 x = ((u32)u) << 16;
  return __builtin_bit_cast(float, x);
}
__device__ __forceinline__ void gl_lds16(const void* g, void* l) {
  __builtin_amdgcn_global_load_lds(
      (const __attribute__((address_space(1))) u32*)g,
      (__attribute__((address_space(3))) u32*)l, 16, 0, 0);
}

// ---------------------------------------------------------------------------
// LayerNorm over last dim (=1024).  obf16: output bf16.  posrow: input is
// w0[c]*(row-(SEQ-1)) + addb[c]  (fused dynamic-pos-bias first layer).
// ---------------------------------------------------------------------------
__global__ __launch_bounds__(256) void ln_kernel(
    const float* __restrict__ in, const float* __restrict__ addb,
    const float* __restrict__ g, const float* __restrict__ bvec,
    void* __restrict__ outv, int silu, int obf16, int posrow) {
  int row = blockIdx.x;
  int t = threadIdx.x;
  float4 x;
  if (posrow) {
    float p = (float)(row - (SEQ - 1));
    float4 wv = ((const float4*)in)[t];
    float4 a = ((const float4*)addb)[t];
    x.x = p * wv.x + a.x; x.y = p * wv.y + a.y;
    x.z = p * wv.z + a.z; x.w = p * wv.w + a.w;
  } else {
    x = ((const float4*)(in + (size_t)row * DIMM))[t];
    if (addb) {
      float4 a = ((const float4*)addb)[t];
      x.x += a.x; x.y += a.y; x.z += a.z; x.w += a.w;
    }
  }
  float s  = x.x + x.y + x.z + x.w;
  float ss = x.x * x.x + x.y * x.y + x.z * x.z + x.w * x.w;
#pragma unroll
  for (int off = 32; off > 0; off >>= 1) {
    s  += __shfl_down(s, off);
    ss += __shfl_down(ss, off);
  }
  __shared__ float rs[4], rss[4];
  int wv_ = t >> 6, lane = t & 63;
  if (lane == 0) { rs[wv_] = s; rss[wv_] = ss; }
  __syncthreads();
  float S  = rs[0] + rs[1] + rs[2] + rs[3];
  float SS = rss[0] + rss[1] + rss[2] + rss[3];
  float mu  = S * (1.0f / DIMM);
  float var = SS * (1.0f / DIMM) - mu * mu;
  float inv = rsqrtf(var + 1e-5f);
  float4 gv = ((const float4*)g)[t];
  float4 bv = ((const float4*)bvec)[t];
  float4 o;
  o.x = (x.x - mu) * inv * gv.x + bv.x;
  o.y = (x.y - mu) * inv * gv.y + bv.y;
  o.z = (x.z - mu) * inv * gv.z + bv.z;
  o.w = (x.w - mu) * inv * gv.w + bv.w;
  if (silu) {
    o.x = o.x / (1.f + expf(-o.x));
    o.y = o.y / (1.f + expf(-o.y));
    o.z = o.z / (1.f + expf(-o.z));
    o.w = o.w / (1.f + expf(-o.w));
  }
  if (obf16) {
    ushort4 ob;
    ob.x = f2bf(o.x); ob.y = f2bf(o.y); ob.z = f2bf(o.z); ob.w = f2bf(o.w);
    ((ushort4*)((u16*)outv + (size_t)row * DIMM))[t] = ob;
  } else {
    ((float4*)((float*)outv + (size_t)row * DIMM))[t] = o;
  }
}

// ---------------------------------------------------------------------------
// Weight convert+transpose: W f32 [K=1024][N] -> WT bf16 [rowOff+N][1024]
// ---------------------------------------------------------------------------
__global__ __launch_bounds__(256) void conv_wT(
    const float* __restrict__ W, u16* __restrict__ WT, int N, int rowOff) {
  __shared__ float tile[32][33];
  const int n0 = blockIdx.x * 32, k0 = blockIdx.y * 32;
  const int tc = threadIdx.x & 31, tr = threadIdx.x >> 5;  // tr 0..7
#pragma unroll
  for (int i = 0; i < 4; ++i)
    tile[tr + i * 8][tc] = W[(size_t)(k0 + tr + i * 8) * N + n0 + tc];
  __syncthreads();
#pragma unroll
  for (int i = 0; i < 4; ++i) {
    int r = tr + i * 8;
    WT[(size_t)(rowOff + n0 + r) * 1024 + k0 + tc] = f2bf(tile[tc][r]);
  }
}

// ---------------------------------------------------------------------------
// bf16 MFMA GEMM (m97 structure): A bf16 [M][K], BT bf16 [N][K], C f32 [M][N]
// ---------------------------------------------------------------------------
__global__ __launch_bounds__(256) void gemm_bf16(
    const u16* __restrict__ A, const u16* __restrict__ BT,
    float* __restrict__ C, int M, int N, int K) {
  __shared__ u16 As[128 * 32];
  __shared__ u16 Bs[128 * 32];
  const int w = threadIdx.x >> 6, lane = threadIdx.x & 63;
  const int lo = lane & 15, hi = lane >> 4;
  const int wr = w >> 1, wc = w & 1;
  const int row0 = blockIdx.y * 128, col0 = blockIdx.x * 128;
  const int srow = lane >> 2;
  const int scol = (lane & 3) * 8;
  f32x4 acc[4][4];
#pragma unroll
  for (int m = 0; m < 4; ++m)
#pragma unroll
    for (int n = 0; n < 4; ++n) acc[m][n] = f32x4{0.f, 0.f, 0.f, 0.f};
  for (int k0 = 0; k0 < K; k0 += 32) {
#pragma unroll
    for (int c = 0; c < 2; ++c) {
      const int base = 32 * w + c * 16;
      gl_lds16(A + (size_t)(row0 + base + srow) * K + k0 + scol,
               &As[base * 32]);
      gl_lds16(BT + (size_t)(col0 + base + srow) * K + k0 + scol,
               &Bs[base * 32]);
    }
    __syncthreads();
    bf16x8 af[4], bg[4];
#pragma unroll
    for (int m = 0; m < 4; ++m)
      af[m] = *(const bf16x8*)&As[(wr * 64 + m * 16 + lo) * 32 + hi * 8];
#pragma unroll
    for (int n = 0; n < 4; ++n)
      bg[n] = *(const bf16x8*)&Bs[(wc * 64 + n * 16 + lo) * 32 + hi * 8];
#pragma unroll
    for (int m = 0; m < 4; ++m)
#pragma unroll
      for (int n = 0; n < 4; ++n)
        acc[m][n] = __builtin_amdgcn_mfma_f32_16x16x32_bf16(af[m], bg[n],
                                                            acc[m][n], 0, 0, 0);
    __syncthreads();
  }
#pragma unroll
  for (int m = 0; m < 4; ++m)
#pragma unroll
    for (int r = 0; r < 4; ++r) {
      const int row = row0 + wr * 64 + m * 16 + hi * 4 + r;
      if (row < M) {
#pragma unroll
        for (int n = 0; n < 4; ++n)
          C[(size_t)row * N + col0 + wc * 64 + n * 16 + lo] = acc[m][n][r];
      }
    }
}

// ---------------------------------------------------------------------------
// q relayout from tmpQKV (stride 1152, cols 0..1023) -> bf16 [b][h][i][d] /8
// ---------------------------------------------------------------------------
__global__ __launch_bounds__(256) void relayout_q(
    const float* __restrict__ tmp, u16* __restrict__ qb) {
  size_t e = (size_t)blockIdx.x * 256 + threadIdx.x;
  int m = (int)(e >> 8), c4 = (int)(e & 255);
  int b = m >> 11, i = m & 2047;
  int h = c4 >> 4, d4 = c4 & 15;
  float4 v = ((const float4*)(tmp + (size_t)m * 1152))[c4];
  const float sc = 0.125f;
  ushort4 o;
  o.x = f2bf(v.x * sc); o.y = f2bf(v.y * sc);
  o.z = f2bf(v.z * sc); o.w = f2bf(v.w * sc);
  ((ushort4*)qb)[((size_t)(b * NHEADS + h) * SEQ + i) * 16 + d4] = o;
}

// kv relayout from tmpQKV cols 1024..1151 -> k bf16 [b][j][d], v^T [b][d][j]
__global__ __launch_bounds__(256) void relayout_kv(
    const float* __restrict__ tmp, u16* __restrict__ kb, u16* __restrict__ vbT) {
  size_t e = (size_t)blockIdx.x * 256 + threadIdx.x;
  int m = (int)(e >> 5), c4 = (int)(e & 31);
  int b = m >> 11, i = m & 2047;
  float4 v = ((const float4*)(tmp + (size_t)m * 1152 + 1024))[c4];
  if (c4 < 16) {
    ushort4 o;
    o.x = f2bf(v.x); o.y = f2bf(v.y); o.z = f2bf(v.z); o.w = f2bf(v.w);
    ((ushort4*)kb)[((size_t)b * NKROWS + (i + 1)) * 16 + c4] = o;
  } else {
    int d = (c4 - 16) * 4;
    size_t base = (size_t)b * DHEAD * NKP + (size_t)d * NKP + (i + 1);
    vbT[base]           = f2bf(v.x);
    vbT[base + NKP]     = f2bf(v.y);
    vbT[base + 2 * NKP] = f2bf(v.z);
    vbT[base + 3 * NKP] = f2bf(v.w);
  }
}

__global__ void fill_null(const float* __restrict__ null_kv,
                          u16* __restrict__ kb, u16* __restrict__ vbT) {
  int b = blockIdx.x, d = threadIdx.x;
  kb[(size_t)b * NKROWS * DHEAD + d] = f2bf(null_kv[d]);
  vbT[(size_t)b * DHEAD * NKP + (size_t)d * NKP] = f2bf(null_kv[DHEAD + d]);
}

// h2: bias_tabT[h][r] = h1[r][:] . w2[:][h] + b2[h]   (transposed table)
__global__ __launch_bounds__(256) void h2_kernel(
    const u16* __restrict__ h1, const float* __restrict__ w2,
    const float* __restrict__ b2, float* __restrict__ bias_tabT) {
  int r = blockIdx.x, t = threadIdx.x;
  int col = t & 15, seg = t >> 4;
  const u16* hr = h1 + (size_t)r * DIMM;
  float acc = 0.f;
  for (int k = seg * 64; k < seg * 64 + 64; ++k)
    acc += bf2f(hr[k]) * w2[(size_t)k * NHEADS + col];
  __shared__ float p[16][16];
  p[seg][col] = acc;
  __syncthreads();
  if (t < 16) {
    float s = 0.f;
#pragma unroll
    for (int q = 0; q < 16; q++) s += p[q][t];
    bias_tabT[(size_t)t * 4096 + r] = s + b2[t];
  }
}

// ---------------------------------------------------------------------------
// Flash attention, MFMA bf16, SWAPPED QK^T (S^T = K@Q^T) so each lane owns
// q-row = lane&15 and 16 key-scores.  Per-lane partial softmax sum, 2-shuffle
// max reduce, defer-max (THR=8).  Block = 4 independent waves, 64 Q rows.
// ---------------------------------------------------------------------------
__global__ __launch_bounds__(256, 4) void flash_attn(
    const u16* __restrict__ qb, const u16* __restrict__ kb,
    const u16* __restrict__ vbT, const float* __restrict__ bias_tabT,
    const float* __restrict__ null_bias, u16* __restrict__ outb) {
  const int qt = gridDim.x - 1 - blockIdx.x;  // heavy blocks first
  const int h = blockIdx.y, b = blockIdx.z;
  const int w = threadIdx.x >> 6, lane = threadIdx.x & 63;
  const int lo = lane & 15, hi = lane >> 4;
  const int q0 = qt * 64, r0 = w * 16;
  const int rq = q0 + r0 + lo;  // this lane's q-row for scores

  __shared__ u16 plds[4][16][72];  // [wave][q][k] (+8 pad)

  // Q as B-frag: col=lo -> q-row rq, k-dim = hi*8+j
  const u16* qrow = qb + (size_t)((b * NHEADS + h) * SEQ + rq) * DHEAD;
  bf16x8 qa0 = *(const bf16x8*)(qrow + hi * 8);
  bf16x8 qa1 = *(const bf16x8*)(qrow + 32 + hi * 8);

  const u16* Kb = kb + (size_t)b * NKROWS * DHEAD;
  const u16* Vb = vbT + (size_t)b * DHEAD * NKP;
  const float* bt = bias_tabT + (size_t)h * 4096;
  const float nb = null_bias[h];

  f32x4 o[4];
#pragma unroll
  for (int nf = 0; nf < 4; ++nf) o[nf] = f32x4{0.f, 0.f, 0.f, 0.f};
  float m_l = -3.0e38f, l_l = 0.f;

  const int nkt = qt + 2;
  for (int kt = 0; kt < nkt; ++kt) {
    const int j0 = kt * 64;
    // ---- K as A-frag: row=lo -> key j0+nf*16+lo ----
    bf16x8 kf0[4], kf1[4];
#pragma unroll
    for (int nf = 0; nf < 4; ++nf) {
      const u16* krow = Kb + (size_t)(j0 + nf * 16 + lo) * DHEAD;
      kf0[nf] = *(const bf16x8*)(krow + hi * 8);
      kf1[nf] = *(const bf16x8*)(krow + 32 + hi * 8);
    }
    // ---- bias prefetch: key = j0+nf*16+hi*4+r, q = rq (coalesced in lo) ----
    float bias[4][4];
#pragma unroll
    for (int nf = 0; nf < 4; ++nf)
#pragma unroll
      for (int r = 0; r < 4; ++r) {
        const int key = j0 + nf * 16 + hi * 4 + r;
        bias[nf][r] = (key == 0) ? nb : bt[rq - key + SEQ];
      }
    // ---- S^T = K @ Q^T ----
    f32x4 s[4];
#pragma unroll
    for (int nf = 0; nf < 4; ++nf) {
      f32x4 acc = f32x4{0.f, 0.f, 0.f, 0.f};
      acc = __builtin_amdgcn_mfma_f32_16x16x32_bf16(kf0[nf], qa0, acc, 0, 0, 0);
      acc = __builtin_amdgcn_mfma_f32_16x16x32_bf16(kf1[nf], qa1, acc, 0, 0, 0);
      s[nf] = acc;
    }
    // ---- V as B-frag (issue early; overlaps softmax) ----
    bf16x8 vf0[4], vf1[4];
#pragma unroll
    for (int nf = 0; nf < 4; ++nf) {
      const u16* vrow = Vb + (size_t)(nf * 16 + lo) * NKP + j0;
      vf0[nf] = *(const bf16x8*)(vrow + hi * 8);
      vf1[nf] = *(const bf16x8*)(vrow + 32 + hi * 8);
    }
    // ---- bias + causal mask (valid iff key <= rq+1) ----
    float tm = -3.0e38f;
#pragma unroll
    for (int nf = 0; nf < 4; ++nf)
#pragma unroll
      for (int r = 0; r < 4; ++r) {
        const int key = j0 + nf * 16 + hi * 4 + r;
        float v = (key <= rq + 1) ? (s[nf][r] + bias[nf][r]) : -3.0e38f;
        s[nf][r] = v;
        tm = fmaxf(tm, v);
      }
    // ---- row max: reduce across hi-groups only (2 shuffles) ----
    tm = fmaxf(tm, __shfl_xor(tm, 16));
    tm = fmaxf(tm, __shfl_xor(tm, 32));
    // ---- defer-max: rescale only when max grows past threshold ----
    if (__any(tm > m_l + 8.0f)) {
      float mn = fmaxf(m_l, tm);
      float sco = __expf(m_l - mn);
      m_l = mn;
      l_l *= sco;
      float scoq[4];
#pragma unroll
      for (int r = 0; r < 4; ++r) scoq[r] = __shfl(sco, hi * 4 + r);
#pragma unroll
      for (int nf = 0; nf < 4; ++nf)
#pragma unroll
        for (int r = 0; r < 4; ++r) o[nf][r] *= scoq[r];
    }
    // ---- exp + per-lane partial sum; pack P to LDS (b64 stores) ----
#pragma unroll
    for (int nf = 0; nf < 4; ++nf) {
      float p0 = __expf(s[nf][0] - m_l);
      float p1 = __expf(s[nf][1] - m_l);
      float p2 = __expf(s[nf][2] - m_l);
      float p3 = __expf(s[nf][3] - m_l);
      l_l += (p0 + p1) + (p2 + p3);
      uint2 pk;
      pk.x = (u32)f2bf(p0) | ((u32)f2bf(p1) << 16);
      pk.y = (u32)f2bf(p2) | ((u32)f2bf(p3) << 16);
      *(uint2*)&plds[w][lo][nf * 16 + hi * 4] = pk;
    }
    // ---- P as A-frag (row=lo=q, k=hi*8+j) ----
    bf16x8 pa0 = *(const bf16x8*)&plds[w][lo][hi * 8];
    bf16x8 pa1 = *(const bf16x8*)&plds[w][lo][32 + hi * 8];
    // ---- O += P @ V ----
#pragma unroll
    for (int nf = 0; nf < 4; ++nf) {
      o[nf] = __builtin_amdgcn_mfma_f32_16x16x32_bf16(pa0, vf0[nf], o[nf], 0, 0, 0);
      o[nf] = __builtin_amdgcn_mfma_f32_16x16x32_bf16(pa1, vf1[nf], o[nf], 0, 0, 0);
    }
  }
  // ---- final l reduce (once) + normalize + write bf16 ----
  float lf = l_l;
  lf += __shfl_xor(lf, 16);
  lf += __shfl_xor(lf, 32);
  float linv = 1.0f / lf;  // for q-row lo
  float linvq[4];
#pragma unroll
  for (int r = 0; r < 4; ++r) linvq[r] = __shfl(linv, hi * 4 + r);
#pragma unroll
  for (int nf = 0; nf < 4; ++nf)
#pragma unroll
    for (int r = 0; r < 4; ++r) {
      const int row = q0 + r0 + hi * 4 + r;
      outb[(size_t)(b * SEQ + row) * DIMM + h * DHEAD + nf * 16 + lo] =
          f2bf(o[nf][r] * linvq[r]);
    }
}

// ---------------------------------------------------------------------------
extern "C" void kernel_launch(void* const* d_in, const int* in_sizes, int n_in,
                              void* d_out, int out_size, void* d_ws,
                              size_t ws_size, hipStream_t stream) {
  const float* x         = (const float*)d_in[0];
  const float* ln_g      = (const float*)d_in[1];
  const float* ln_b      = (const float*)d_in[2];
  const float* Wq        = (const float*)d_in[3];
  const float* Wkv       = (const float*)d_in[4];
  const float* null_kv   = (const float*)d_in[5];
  const float* null_bias = (const float*)d_in[6];
  const float* pb_w0     = (const float*)d_in[7];
  const float* pb_b0     = (const float*)d_in[8];
  const float* pb_ln0_g  = (const float*)d_in[9];
  const float* pb_ln0_b  = (const float*)d_in[10];
  const float* pb_w1     = (const float*)d_in[11];
  const float* pb_b1     = (const float*)d_in[12];
  const float* pb_ln1_g  = (const float*)d_in[13];
  const float* pb_ln1_b  = (const float*)d_in[14];
  const float* pb_w2     = (const float*)d_in[15];
  const float* pb_b2     = (const float*)d_in[16];
  const float* Wo        = (const float*)d_in[17];
  const float* out_ln_g  = (const float*)d_in[18];
  const float* out_ln_b  = (const float*)d_in[19];
  float* out = (float*)d_out;

  char* ws = (char*)d_ws;
  float* regA      = (float*)(ws);                      // f32 4096x1152
  u16*   h1_bf     = (u16*)(ws + 18874368);             // bf16 4095x1024
  u16*   regC      = (u16*)(ws + 35651584);             // bf16 4096x1024
  u16*   qb        = (u16*)(ws + 44040192);             // bf16 q
  u16*   kb        = (u16*)(ws + 52428800);             // bf16 K padded
  u16*   vbT       = (u16*)(ws + 52969472);             // bf16 V^T padded
  u16*   wqkvT     = (u16*)(ws + 53510144);             // 1152x1024 bf16
  u16*   w1T       = (u16*)(ws + 55869440);             // 1024x1024 bf16
  u16*   woT       = (u16*)(ws + 57966592);             // 1024x1024 bf16
  float* bias_tabT = (float*)(ws + 60063744);           // f32 [16][4096]

  hipMemsetAsync((void*)kb, 0, 1081344, stream);

  conv_wT<<<dim3(32, 32), 256, 0, stream>>>(Wq, wqkvT, 1024, 0);
  conv_wT<<<dim3(4, 32), 256, 0, stream>>>(Wkv, wqkvT, 128, 1024);
  conv_wT<<<dim3(32, 32), 256, 0, stream>>>(pb_w1, w1T, 1024, 0);
  conv_wT<<<dim3(32, 32), 256, 0, stream>>>(Wo, woT, 1024, 0);

  // 1. xn = LN(x) -> bf16
  ln_kernel<<<ROWS, 256, 0, stream>>>(x, nullptr, ln_g, ln_b, regC, 0, 1, 0);
  // 2. fused q|kv GEMM
  gemm_bf16<<<dim3(9, 32), 256, 0, stream>>>(regC, wqkvT, regA, ROWS, 1152,
                                             1024);
  relayout_q<<<4096, 256, 0, stream>>>(regA, qb);
  relayout_kv<<<512, 256, 0, stream>>>(regA, kb, vbT);
  fill_null<<<2, 64, 0, stream>>>(null_kv, kb, vbT);
  // 3. pos-bias MLP (first layer fused into LN)
  ln_kernel<<<PBROWS, 256, 0, stream>>>(pb_w0, pb_b0, pb_ln0_g, pb_ln0_b, regC,
                                        1, 1, 1);
  gemm_bf16<<<dim3(8, 32), 256, 0, stream>>>(regC, w1T, regA, PBROWS, 1024,
                                             1024);
  ln_kernel<<<PBROWS, 256, 0, stream>>>(regA, pb_b1, pb_ln1_g, pb_ln1_b, h1_bf,
                                        1, 1, 0);
  h2_kernel<<<PBROWS, 256, 0, stream>>>(h1_bf, pb_w2, pb_b2, bias_tabT);
  // 4. flash attention -> regC (bf16, [b][n][h*64+d])
  flash_attn<<<dim3(SEQ / 64, NHEADS, BATCH), 256, 0, stream>>>(
      qb, kb, vbT, bias_tabT, null_bias, regC);
  // 5. out = LN(attn @ Wo)
  gemm_bf16<<<dim3(8, 32), 256, 0, stream>>>(regC, woT, regA, ROWS, 1024, 1024);
  ln_kernel<<<ROWS, 256, 0, stream>>>(regA, nullptr, out_ln_g, out_ln_b, out, 0,
                                      0, 0);
}